// Round 3
// baseline (588.756 us; speedup 1.0000x reference)
//
#include <hip/hip_runtime.h>
#include <math.h>

#define HH 256
#define WW 256
#define BC 512   // B*C = 8*64
#define QN 100
#define RBAND 16 // output rows per wave

// ---------------------------------------------------------------------------
// Kernel 1: per-(b,c) 18x100 GEMM + q output + derived conv coefficients.
// coef layout per bc (stride 32 floats): [0..8]=former, [9..17]=wk,
// [18..26]=|wk|, [27..29]=column sums of wk (kept for layout compat).
// ---------------------------------------------------------------------------
__global__ __launch_bounds__(128) void prep_kernel(
    const float* __restrict__ query,   // (100, 8, 64) = (100, 512)
    const float* __restrict__ Wl,      // (18, 100)
    const float* __restrict__ bl,      // (18,)
    const float* __restrict__ Wd,      // (100, 18)
    const float* __restrict__ bd,      // (100,)
    float* __restrict__ qout,          // (100, 512) region of d_out
    float* __restrict__ coef)          // (512, 32) in d_ws
{
    const int bc = blockIdx.x;
    const int t  = threadIdx.x;
    __shared__ float qcol[QN];
    __shared__ float c18[18];

    if (t < QN) qcol[t] = query[t * BC + bc];
    __syncthreads();

    if (t < 18) {
        float acc = bl[t];
        const float* wrow = Wl + t * QN;
        #pragma unroll 4
        for (int qi = 0; qi < QN; ++qi) acc += qcol[qi] * wrow[qi];
        c18[t] = acc;
    }
    __syncthreads();

    if (t < QN) {
        float acc = bd[t];
        const float* wrow = Wd + t * 18;
        #pragma unroll
        for (int k = 0; k < 18; ++k) acc += c18[k] * wrow[k];
        qout[t * BC + bc] = acc;   // q.transpose(2,0,1) layout
    }

    if (t < 18) {
        coef[bc * 32 + t] = c18[t];                      // former / wk
    } else if (t < 27) {
        coef[bc * 32 + t] = fabsf(c18[t - 9]);           // |wk|
    } else if (t < 30) {
        int j = t - 27;
        coef[bc * 32 + t] = c18[9 + j] + c18[12 + j] + c18[15 + j]; // colsum
    }
}

// ---------------------------------------------------------------------------
// Kernel 2: LDS-free streaming stencil. One wave64 spans the full 256-col
// image width (4 cols/lane); each wave streams a 16-row band with rolling
// register windows:
//   v[s][6]: value rows, slot(r) = (r - r0 + 2) & 3, cols [4x-1 .. 4x+4]
//   d[s][6]: diff  rows, slot(r) = (r - r0 + 1) & 3
// Column neighbors via __shfl (image-edge cols are zero = SAME padding).
// Iteration for output row h:  load value(h+2) -> compute diff(h+1) ->
// output(h).  Algebraic fold: res - res_diff =
//   sum_b wk[b]*(vd(h-1)-vd(h)) + wk[6+b]*(vd(h+1)-vd(h)).
// All 9-term dots are tree-reassociated (3 independent 3-FMA chains) to cut
// the dependent-latency path ~2x.  No __syncthreads, no LDS.
// RBAND=16 -> 8192 waves = 8 waves/SIMD; launch_bounds(256,8) pins VGPR<=64.
// ---------------------------------------------------------------------------
__global__ __launch_bounds__(256, 8) void fused_kernel(
    const float* __restrict__ value,   // (512, 256, 256)
    const float* __restrict__ coef,    // (512, 32)
    float* __restrict__ yout)          // (512, 256, 256) region of d_out
{
    const int bc   = blockIdx.z;
    const int wave = threadIdx.x >> 6;
    const int lane = threadIdx.x & 63;
    const int band = blockIdx.x * 4 + wave;
    const int r0   = band * RBAND;
    const int x4   = lane << 2;

    const bool l0  = (lane == 0);
    const bool l63 = (lane == 63);

    // coefficients: block-uniform address -> scalar loads
    const float* cp = coef + bc * 32;
    float fco[9], awk[9], wk6[6];
    #pragma unroll
    for (int i = 0; i < 9; ++i) { fco[i] = cp[i]; awk[i] = cp[18 + i]; }
    wk6[0] = cp[9];  wk6[1] = cp[10]; wk6[2] = cp[11];
    wk6[3] = cp[15]; wk6[4] = cp[16]; wk6[5] = cp[17];

    const float* vbase = value + (size_t)bc * (HH * WW);
    float*       obase = yout  + (size_t)bc * (HH * WW);

    float v[4][6];
    float d[4][6];

    // tree-form 9-term dot: 3 independent 3-FMA chains, then 2 adds
    auto DOT9 = [](const float* f, const float* ra, const float* rb,
                   const float* rc, int c) -> float {
        float s0 = fmaf(f[2], ra[c + 2], fmaf(f[1], ra[c + 1], f[0] * ra[c]));
        float s1 = fmaf(f[5], rb[c + 2], fmaf(f[4], rb[c + 1], f[3] * rb[c]));
        float s2 = fmaf(f[8], rc[c + 2], fmaf(f[7], rc[c + 1], f[6] * rc[c]));
        return (s0 + s1) + s2;
    };

    // load value row r into 6-wide register row (cols 4x-1 .. 4x+4)
    auto LOADV = [&](int r, float* row) {
        if ((unsigned)r < HH) {
            const float4 q = *(const float4*)(vbase + r * WW + x4);
            row[1] = q.x; row[2] = q.y; row[3] = q.z; row[4] = q.w;
            float left  = __shfl_up(q.w, 1);
            float right = __shfl_down(q.x, 1);
            row[0] = l0  ? 0.f : left;   // image col -1 -> 0
            row[5] = l63 ? 0.f : right;  // image col 256 -> 0
        } else {
            #pragma unroll
            for (int m = 0; m < 6; ++m) row[m] = 0.f;
        }
    };

    // diff row r from value rows r-1 (va), r (vb), r+1 (vc)
    auto COMPD = [&](int r, const float* va, const float* vb, const float* vc,
                     float* drow) {
        if ((unsigned)r < HH) {
            float d4[4];
            #pragma unroll
            for (int c = 0; c < 4; ++c) {
                float yt = DOT9(fco, va, vb, vc, c);
                float e = vb[c + 1] - yt;
                d4[c] = __expf(-e * e);
            }
            drow[1] = d4[0]; drow[2] = d4[1]; drow[3] = d4[2]; drow[4] = d4[3];
            float left  = __shfl_up(d4[3], 1);
            float right = __shfl_down(d4[0], 1);
            drow[0] = l0  ? 0.f : left;
            drow[5] = l63 ? 0.f : right;
        } else {
            #pragma unroll
            for (int m = 0; m < 6; ++m) drow[m] = 0.f;
        }
    };

    // output row h from value rows h-1..h+1 (vp,vq,vs) and diff rows (dp,dq,ds)
    auto OUTROW = [&](int h, const float* vp, const float* vq, const float* vs,
                      const float* dp, const float* dq, const float* ds) {
        float dv0[6], dv2[6];
        #pragma unroll
        for (int m = 0; m < 6; ++m) {
            float mid = dq[m] * vq[m];
            dv0[m] = fmaf(dp[m], vp[m], -mid);
            dv2[m] = fmaf(ds[m], vs[m], -mid);
        }
        float4 o;
        #pragma unroll
        for (int c = 0; c < 4; ++c) {
            float yt  = DOT9(fco, vp, vq, vs, c);
            // yd9: tree form, fold +1e-10 into first chain
            float y0 = fmaf(awk[2], dp[c + 2],
                       fmaf(awk[1], dp[c + 1], fmaf(awk[0], dp[c], 1e-10f)));
            float y1 = fmaf(awk[5], dq[c + 2],
                       fmaf(awk[4], dq[c + 1], awk[3] * dq[c]));
            float y2 = fmaf(awk[8], ds[c + 2],
                       fmaf(awk[7], ds[c + 1], awk[6] * ds[c]));
            float yd9 = (y0 + y1) + y2;
            float n0 = fmaf(wk6[2], dv0[c + 2],
                       fmaf(wk6[1], dv0[c + 1], wk6[0] * dv0[c]));
            float n1 = fmaf(wk6[5], dv2[c + 2],
                       fmaf(wk6[4], dv2[c + 1], wk6[3] * dv2[c]));
            float num = n0 + n1;
            (&o.x)[c] = yt - num * __builtin_amdgcn_rcpf(yd9);
        }
        *(float4*)(obase + h * WW + x4) = o;
    };

    // ---- prologue: value rows r0-2 .. r0+1, diff rows r0-1, r0 ----
    LOADV(r0 - 2, v[0]);
    LOADV(r0 - 1, v[1]);
    LOADV(r0,     v[2]);
    LOADV(r0 + 1, v[3]);
    COMPD(r0 - 1, v[0], v[1], v[2], d[0]);
    COMPD(r0,     v[1], v[2], v[3], d[1]);

    // ---- main loop: RBAND rows, unrolled x4 so all slot indices are static ----
    for (int io = 0; io < RBAND; io += 4) {
        #pragma unroll
        for (int j = 0; j < 4; ++j) {
            const int h = r0 + io + j;
            // v slot(r) = (r - r0 + 2) & 3; io % 4 == 0 so reduce mod j only
            LOADV(h + 2, v[j & 3]);                         // drops row h-2
            COMPD(h + 1, v[(j + 2) & 3], v[(j + 3) & 3], v[j & 3],
                  d[(j + 2) & 3]);                          // drops diff h-3
            OUTROW(h, v[(j + 1) & 3], v[(j + 2) & 3], v[(j + 3) & 3],
                   d[j & 3], d[(j + 1) & 3], d[(j + 2) & 3]);
        }
    }
}

// ---------------------------------------------------------------------------
extern "C" void kernel_launch(void* const* d_in, const int* in_sizes, int n_in,
                              void* d_out, int out_size, void* d_ws, size_t ws_size,
                              hipStream_t stream) {
    const float* query = (const float*)d_in[0];   // (100,8,64)
    const float* value = (const float*)d_in[1];   // (8,64,256,256)
    // d_in[2..4]: unused scalars
    const float* Wl    = (const float*)d_in[5];   // (18,100)
    const float* bl    = (const float*)d_in[6];   // (18,)
    const float* Wd    = (const float*)d_in[7];   // (100,18)
    const float* bd    = (const float*)d_in[8];   // (100,)

    float* out   = (float*)d_out;
    float* qout  = out;                 // first 100*512 floats
    float* yout  = out + QN * BC;       // then 512*256*256 floats
    float* coef  = (float*)d_ws;        // 512*32 floats = 64 KB

    prep_kernel<<<BC, 128, 0, stream>>>(query, Wl, bl, Wd, bd, qout, coef);

    // 16 bands of 16 rows per image; 4 waves (bands) per block
    dim3 grid(HH / (RBAND * 4), 1, BC);
    fused_kernel<<<grid, 256, 0, stream>>>(value, coef, yout);
}

// Round 4
// 271.919 us; speedup vs baseline: 2.1652x; 2.1652x over previous
//
#include <hip/hip_runtime.h>
#include <math.h>

#define HH 256
#define WW 256
#define BC 512   // B*C = 8*64
#define QN 100
#define RBAND 16 // output rows per wave

// ---------------------------------------------------------------------------
// Kernel 1: per-(b,c) 18x100 GEMM + q output + derived conv coefficients.
// coef layout per bc (stride 32 floats): [0..8]=former, [9..17]=wk,
// [18..26]=|wk|, [27..29]=column sums of wk (kept for layout compat).
// ---------------------------------------------------------------------------
__global__ __launch_bounds__(128) void prep_kernel(
    const float* __restrict__ query,   // (100, 8, 64) = (100, 512)
    const float* __restrict__ Wl,      // (18, 100)
    const float* __restrict__ bl,      // (18,)
    const float* __restrict__ Wd,      // (100, 18)
    const float* __restrict__ bd,      // (100,)
    float* __restrict__ qout,          // (100, 512) region of d_out
    float* __restrict__ coef)          // (512, 32) in d_ws
{
    const int bc = blockIdx.x;
    const int t  = threadIdx.x;
    __shared__ float qcol[QN];
    __shared__ float c18[18];

    if (t < QN) qcol[t] = query[t * BC + bc];
    __syncthreads();

    if (t < 18) {
        float acc = bl[t];
        const float* wrow = Wl + t * QN;
        #pragma unroll 4
        for (int qi = 0; qi < QN; ++qi) acc += qcol[qi] * wrow[qi];
        c18[t] = acc;
    }
    __syncthreads();

    if (t < QN) {
        float acc = bd[t];
        const float* wrow = Wd + t * 18;
        #pragma unroll
        for (int k = 0; k < 18; ++k) acc += c18[k] * wrow[k];
        qout[t * BC + bc] = acc;   // q.transpose(2,0,1) layout
    }

    if (t < 18) {
        coef[bc * 32 + t] = c18[t];                      // former / wk
    } else if (t < 27) {
        coef[bc * 32 + t] = fabsf(c18[t - 9]);           // |wk|
    } else if (t < 30) {
        int j = t - 27;
        coef[bc * 32 + t] = c18[9 + j] + c18[12 + j] + c18[15 + j]; // colsum
    }
}

// ---------------------------------------------------------------------------
// Kernel 2: LDS-free streaming stencil. One wave64 spans the full 256-col
// image width (4 cols/lane); each wave streams a 16-row band with rolling
// register windows:
//   v[s][6]: value rows, slot(r) = (r - r0 + 2) & 3, cols [4x-1 .. 4x+4]
//   d[s][6]: diff  rows, slot(r) = (r - r0 + 1) & 3
// Column neighbors via __shfl (image-edge cols are zero = SAME padding).
// Iteration for output row h:  load value(h+2) -> compute diff(h+1) ->
// output(h).  Algebraic fold: res - res_diff =
//   sum_b wk[b]*(vd(h-1)-vd(h)) + wk[6+b]*(vd(h+1)-vd(h)).
// All 9-term dots are tree-reassociated (3 independent 3-FMA chains).
// No __syncthreads, no LDS.
// RBAND=16 -> 2048 blocks = 8192 waves = 8 waves/SIMD when VGPR<=64.
// launch_bounds minimum stays 4: pinning 8 forced VGPR=32 and spilled
// (round-3 post-mortem: FETCH 622 MB of scratch traffic, VALUBusy 12%).
// ---------------------------------------------------------------------------
__global__ __launch_bounds__(256, 4) void fused_kernel(
    const float* __restrict__ value,   // (512, 256, 256)
    const float* __restrict__ coef,    // (512, 32)
    float* __restrict__ yout)          // (512, 256, 256) region of d_out
{
    const int bc   = blockIdx.z;
    const int wave = threadIdx.x >> 6;
    const int lane = threadIdx.x & 63;
    const int band = blockIdx.x * 4 + wave;
    const int r0   = band * RBAND;
    const int x4   = lane << 2;

    const bool l0  = (lane == 0);
    const bool l63 = (lane == 63);

    // coefficients: block-uniform address -> scalar loads
    const float* cp = coef + bc * 32;
    float fco[9], awk[9], wk6[6];
    #pragma unroll
    for (int i = 0; i < 9; ++i) { fco[i] = cp[i]; awk[i] = cp[18 + i]; }
    wk6[0] = cp[9];  wk6[1] = cp[10]; wk6[2] = cp[11];
    wk6[3] = cp[15]; wk6[4] = cp[16]; wk6[5] = cp[17];

    const float* vbase = value + (size_t)bc * (HH * WW);
    float*       obase = yout  + (size_t)bc * (HH * WW);

    float v[4][6];
    float d[4][6];

    // tree-form 9-term dot: 3 independent 3-FMA chains, then 2 adds
    auto DOT9 = [](const float* f, const float* ra, const float* rb,
                   const float* rc, int c) -> float {
        float s0 = fmaf(f[2], ra[c + 2], fmaf(f[1], ra[c + 1], f[0] * ra[c]));
        float s1 = fmaf(f[5], rb[c + 2], fmaf(f[4], rb[c + 1], f[3] * rb[c]));
        float s2 = fmaf(f[8], rc[c + 2], fmaf(f[7], rc[c + 1], f[6] * rc[c]));
        return (s0 + s1) + s2;
    };

    // load value row r into 6-wide register row (cols 4x-1 .. 4x+4)
    auto LOADV = [&](int r, float* row) {
        if ((unsigned)r < HH) {
            const float4 q = *(const float4*)(vbase + r * WW + x4);
            row[1] = q.x; row[2] = q.y; row[3] = q.z; row[4] = q.w;
            float left  = __shfl_up(q.w, 1);
            float right = __shfl_down(q.x, 1);
            row[0] = l0  ? 0.f : left;   // image col -1 -> 0
            row[5] = l63 ? 0.f : right;  // image col 256 -> 0
        } else {
            #pragma unroll
            for (int m = 0; m < 6; ++m) row[m] = 0.f;
        }
    };

    // diff row r from value rows r-1 (va), r (vb), r+1 (vc)
    auto COMPD = [&](int r, const float* va, const float* vb, const float* vc,
                     float* drow) {
        if ((unsigned)r < HH) {
            float d4[4];
            #pragma unroll
            for (int c = 0; c < 4; ++c) {
                float yt = DOT9(fco, va, vb, vc, c);
                float e = vb[c + 1] - yt;
                d4[c] = __expf(-e * e);
            }
            drow[1] = d4[0]; drow[2] = d4[1]; drow[3] = d4[2]; drow[4] = d4[3];
            float left  = __shfl_up(d4[3], 1);
            float right = __shfl_down(d4[0], 1);
            drow[0] = l0  ? 0.f : left;
            drow[5] = l63 ? 0.f : right;
        } else {
            #pragma unroll
            for (int m = 0; m < 6; ++m) drow[m] = 0.f;
        }
    };

    // output row h from value rows h-1..h+1 (vp,vq,vs) and diff rows (dp,dq,ds)
    auto OUTROW = [&](int h, const float* vp, const float* vq, const float* vs,
                      const float* dp, const float* dq, const float* ds) {
        float dv0[6], dv2[6];
        #pragma unroll
        for (int m = 0; m < 6; ++m) {
            float mid = dq[m] * vq[m];
            dv0[m] = fmaf(dp[m], vp[m], -mid);
            dv2[m] = fmaf(ds[m], vs[m], -mid);
        }
        float4 o;
        #pragma unroll
        for (int c = 0; c < 4; ++c) {
            float yt  = DOT9(fco, vp, vq, vs, c);
            // yd9: tree form, fold +1e-10 into first chain
            float y0 = fmaf(awk[2], dp[c + 2],
                       fmaf(awk[1], dp[c + 1], fmaf(awk[0], dp[c], 1e-10f)));
            float y1 = fmaf(awk[5], dq[c + 2],
                       fmaf(awk[4], dq[c + 1], awk[3] * dq[c]));
            float y2 = fmaf(awk[8], ds[c + 2],
                       fmaf(awk[7], ds[c + 1], awk[6] * ds[c]));
            float yd9 = (y0 + y1) + y2;
            float n0 = fmaf(wk6[2], dv0[c + 2],
                       fmaf(wk6[1], dv0[c + 1], wk6[0] * dv0[c]));
            float n1 = fmaf(wk6[5], dv2[c + 2],
                       fmaf(wk6[4], dv2[c + 1], wk6[3] * dv2[c]));
            float num = n0 + n1;
            (&o.x)[c] = yt - num * __builtin_amdgcn_rcpf(yd9);
        }
        *(float4*)(obase + h * WW + x4) = o;
    };

    // ---- prologue: value rows r0-2 .. r0+1, diff rows r0-1, r0 ----
    LOADV(r0 - 2, v[0]);
    LOADV(r0 - 1, v[1]);
    LOADV(r0,     v[2]);
    LOADV(r0 + 1, v[3]);
    COMPD(r0 - 1, v[0], v[1], v[2], d[0]);
    COMPD(r0,     v[1], v[2], v[3], d[1]);

    // ---- main loop: RBAND rows, unrolled x4 so all slot indices are static ----
    for (int io = 0; io < RBAND; io += 4) {
        #pragma unroll
        for (int j = 0; j < 4; ++j) {
            const int h = r0 + io + j;
            // v slot(r) = (r - r0 + 2) & 3; io % 4 == 0 so reduce mod j only
            LOADV(h + 2, v[j & 3]);                         // drops row h-2
            COMPD(h + 1, v[(j + 2) & 3], v[(j + 3) & 3], v[j & 3],
                  d[(j + 2) & 3]);                          // drops diff h-3
            OUTROW(h, v[(j + 1) & 3], v[(j + 2) & 3], v[(j + 3) & 3],
                   d[j & 3], d[(j + 1) & 3], d[(j + 2) & 3]);
        }
    }
}

// ---------------------------------------------------------------------------
extern "C" void kernel_launch(void* const* d_in, const int* in_sizes, int n_in,
                              void* d_out, int out_size, void* d_ws, size_t ws_size,
                              hipStream_t stream) {
    const float* query = (const float*)d_in[0];   // (100,8,64)
    const float* value = (const float*)d_in[1];   // (8,64,256,256)
    // d_in[2..4]: unused scalars
    const float* Wl    = (const float*)d_in[5];   // (18,100)
    const float* bl    = (const float*)d_in[6];   // (18,)
    const float* Wd    = (const float*)d_in[7];   // (100,18)
    const float* bd    = (const float*)d_in[8];   // (100,)

    float* out   = (float*)d_out;
    float* qout  = out;                 // first 100*512 floats
    float* yout  = out + QN * BC;       // then 512*256*256 floats
    float* coef  = (float*)d_ws;        // 512*32 floats = 64 KB

    prep_kernel<<<BC, 128, 0, stream>>>(query, Wl, bl, Wd, bd, qout, coef);

    // 16 bands of 16 rows per image; 4 waves (bands) per block
    dim3 grid(HH / (RBAND * 4), 1, BC);
    fused_kernel<<<grid, 256, 0, stream>>>(value, coef, yout);
}

// Round 5
// 268.648 us; speedup vs baseline: 2.1916x; 1.0122x over previous
//
#include <hip/hip_runtime.h>
#include <math.h>

#define HH 256
#define WW 256
#define BC 512   // B*C = 8*64
#define QN 100
#define RBAND 16 // output rows per wave

// ---------------------------------------------------------------------------
// Kernel 1: per-(b,c) 18x100 GEMM + q output + derived conv coefficients.
// coef layout per bc (stride 32 floats): [0..8]=former, [9..17]=wk,
// [18..26]=|wk|, [27..29]=column sums of wk (kept for layout compat).
// ---------------------------------------------------------------------------
__global__ __launch_bounds__(128) void prep_kernel(
    const float* __restrict__ query,   // (100, 8, 64) = (100, 512)
    const float* __restrict__ Wl,      // (18, 100)
    const float* __restrict__ bl,      // (18,)
    const float* __restrict__ Wd,      // (100, 18)
    const float* __restrict__ bd,      // (100,)
    float* __restrict__ qout,          // (100, 512) region of d_out
    float* __restrict__ coef)          // (512, 32) in d_ws
{
    const int bc = blockIdx.x;
    const int t  = threadIdx.x;
    __shared__ float qcol[QN];
    __shared__ float c18[18];

    if (t < QN) qcol[t] = query[t * BC + bc];
    __syncthreads();

    if (t < 18) {
        float acc = bl[t];
        const float* wrow = Wl + t * QN;
        #pragma unroll 4
        for (int qi = 0; qi < QN; ++qi) acc += qcol[qi] * wrow[qi];
        c18[t] = acc;
    }
    __syncthreads();

    if (t < QN) {
        float acc = bd[t];
        const float* wrow = Wd + t * 18;
        #pragma unroll
        for (int k = 0; k < 18; ++k) acc += c18[k] * wrow[k];
        qout[t * BC + bc] = acc;   // q.transpose(2,0,1) layout
    }

    if (t < 18) {
        coef[bc * 32 + t] = c18[t];                      // former / wk
    } else if (t < 27) {
        coef[bc * 32 + t] = fabsf(c18[t - 9]);           // |wk|
    } else if (t < 30) {
        int j = t - 27;
        coef[bc * 32 + t] = c18[9 + j] + c18[12 + j] + c18[15 + j]; // colsum
    }
}

// ---------------------------------------------------------------------------
// Kernel 2: LDS-free streaming stencil, software-pipelined row loads.
// One wave64 spans the full 256-col image width (4 cols/lane); each wave
// streams a 16-row band.  Register state:
//   v[4][6] : finished value rows h-1..h+2 (halo cols included, edge-masked)
//   raw[6]  : in-flight value row (issued one iteration ahead -> the vmcnt
//             wait lands a full iteration after issue: latency hidden)
//   d[4][6] : diff rows h-1..h+1
//   yt2[2][4]: former-conv row reuse — COMPD(h) saves yt, OUTROW(h) consumes
//             it next iteration (saves a full 9-term dot per pixel).
// Column halos are fetched as 2 extra dword loads with per-lane clamped
// offsets (same cache lines as neighbor lanes' float4 -> no extra HBM) —
// no shfl on the load path.  Diff halos still use 2 shfl per row.
// Iteration j (h = r0+j):  FINISH raw->v  |  ISSUE row h+3  |
//   COMPD diff(h+1) (+save yt)  |  OUTROW(h) (reuses yt(h)).
// ---------------------------------------------------------------------------
__global__ __launch_bounds__(256, 4) void fused_kernel(
    const float* __restrict__ value,   // (512, 256, 256)
    const float* __restrict__ coef,    // (512, 32)
    float* __restrict__ yout)          // (512, 256, 256) region of d_out
{
    const int bc   = blockIdx.z;
    const int wave = threadIdx.x >> 6;
    const int lane = threadIdx.x & 63;
    const int band = blockIdx.x * 4 + wave;
    const int r0   = band * RBAND;
    const int x4   = lane << 2;

    const bool l0  = (lane == 0);
    const bool l63 = (lane == 63);
    // clamped halo columns (stay inside the row; masked to 0 after load)
    const int xl = l0  ? 0   : x4 - 1;
    const int xr = l63 ? 255 : x4 + 4;

    // coefficients: block-uniform address -> scalar (SGPR) loads
    const float* cp = coef + bc * 32;
    float fco[9], awk[9], wk6[6];
    #pragma unroll
    for (int i = 0; i < 9; ++i) { fco[i] = cp[i]; awk[i] = cp[18 + i]; }
    wk6[0] = cp[9];  wk6[1] = cp[10]; wk6[2] = cp[11];
    wk6[3] = cp[15]; wk6[4] = cp[16]; wk6[5] = cp[17];

    const float* vbase = value + (size_t)bc * (HH * WW);
    float*       obase = yout  + (size_t)bc * (HH * WW);

    float v[4][6];
    float raw[6];
    float d[4][6];
    float yt2[2][4];

    // tree-form 9-term dot: 3 independent 3-FMA chains, then 2 adds
    auto DOT9 = [](const float* f, const float* ra, const float* rb,
                   const float* rc, int c) -> float {
        float s0 = fmaf(f[2], ra[c + 2], fmaf(f[1], ra[c + 1], f[0] * ra[c]));
        float s1 = fmaf(f[5], rb[c + 2], fmaf(f[4], rb[c + 1], f[3] * rb[c]));
        float s2 = fmaf(f[8], rc[c + 2], fmaf(f[7], rc[c + 1], f[6] * rc[c]));
        return (s0 + s1) + s2;
    };

    // issue row r's loads into raw (no masking, no wait — consumed next iter)
    auto ISSUE = [&](int r) {
        if ((unsigned)r < HH) {
            const float* rowp = vbase + r * WW;
            const float4 q = *(const float4*)(rowp + x4);
            raw[0] = rowp[xl];
            raw[1] = q.x; raw[2] = q.y; raw[3] = q.z; raw[4] = q.w;
            raw[5] = rowp[xr];
        } else {
            #pragma unroll
            for (int m = 0; m < 6; ++m) raw[m] = 0.f;
        }
    };

    // edge-mask raw and retire it into a finished v row
    auto FINISH = [&](float* vr) {
        vr[0] = l0 ? 0.f : raw[0];
        vr[1] = raw[1]; vr[2] = raw[2]; vr[3] = raw[3]; vr[4] = raw[4];
        vr[5] = l63 ? 0.f : raw[5];
    };

    // prologue row load: issue + finish immediately (independent loads batch)
    auto LOADV = [&](int r, float* vr) { ISSUE(r); FINISH(vr); };

    // diff row r from value rows r-1 (va), r (vb), r+1 (vc); saves yt(r)
    auto COMPD = [&](int r, const float* va, const float* vb, const float* vc,
                     float* drow, float* ytr) {
        if ((unsigned)r < HH) {
            float d4[4];
            #pragma unroll
            for (int c = 0; c < 4; ++c) {
                float yt = DOT9(fco, va, vb, vc, c);
                ytr[c] = yt;
                float e = vb[c + 1] - yt;
                d4[c] = __expf(-e * e);
            }
            drow[1] = d4[0]; drow[2] = d4[1]; drow[3] = d4[2]; drow[4] = d4[3];
            float left  = __shfl_up(d4[3], 1);
            float right = __shfl_down(d4[0], 1);
            drow[0] = l0  ? 0.f : left;
            drow[5] = l63 ? 0.f : right;
        } else {
            #pragma unroll
            for (int m = 0; m < 6; ++m) drow[m] = 0.f;
        }
    };

    // output row h; yt(h) comes precomputed from COMPD(h) via ytr
    auto OUTROW = [&](int h, const float* vp, const float* vq, const float* vs,
                      const float* dp, const float* dq, const float* ds,
                      const float* ytr) {
        float dv0[6], dv2[6];
        #pragma unroll
        for (int m = 0; m < 6; ++m) {
            float mid = dq[m] * vq[m];
            dv0[m] = fmaf(dp[m], vp[m], -mid);
            dv2[m] = fmaf(ds[m], vs[m], -mid);
        }
        float4 o;
        #pragma unroll
        for (int c = 0; c < 4; ++c) {
            float y0 = fmaf(awk[2], dp[c + 2],
                       fmaf(awk[1], dp[c + 1], fmaf(awk[0], dp[c], 1e-10f)));
            float y1 = fmaf(awk[5], dq[c + 2],
                       fmaf(awk[4], dq[c + 1], awk[3] * dq[c]));
            float y2 = fmaf(awk[8], ds[c + 2],
                       fmaf(awk[7], ds[c + 1], awk[6] * ds[c]));
            float yd9 = (y0 + y1) + y2;
            float n0 = fmaf(wk6[2], dv0[c + 2],
                       fmaf(wk6[1], dv0[c + 1], wk6[0] * dv0[c]));
            float n1 = fmaf(wk6[5], dv2[c + 2],
                       fmaf(wk6[4], dv2[c + 1], wk6[3] * dv2[c]));
            float num = n0 + n1;
            (&o.x)[c] = fmaf(-num, __builtin_amdgcn_rcpf(yd9), ytr[c]);
        }
        *(float4*)(obase + h * WW + x4) = o;
    };

    // ---- prologue: value rows r0-2 .. r0+1; diff rows r0-1, r0 (+yt) ----
    LOADV(r0 - 2, v[0]);
    LOADV(r0 - 1, v[1]);
    LOADV(r0,     v[2]);
    LOADV(r0 + 1, v[3]);
    COMPD(r0 - 1, v[0], v[1], v[2], d[0], yt2[1]);
    COMPD(r0,     v[1], v[2], v[3], d[1], yt2[0]);
    ISSUE(r0 + 2);   // start the pipeline

    // ---- main loop: RBAND rows, unrolled x4 so all slot indices are static.
    // v slot(r) = (r - r0 + 2) & 3 ; d slot(r) = (r - r0 + 1) & 3 ;
    // yt slot(r) = (r - r0) & 1.
    for (int io = 0; io < RBAND; io += 4) {
        #pragma unroll
        for (int j4 = 0; j4 < 4; ++j4) {
            const int j = io + j4;
            const int h = r0 + j;
            FINISH(v[j4 & 3]);                         // retire row h+2
            ISSUE(h + 3);                              // next row in flight
            COMPD(h + 1, v[(j4 + 2) & 3], v[(j4 + 3) & 3], v[j4 & 3],
                  d[(j4 + 2) & 3], yt2[(j + 1) & 1]);
            OUTROW(h, v[(j4 + 1) & 3], v[(j4 + 2) & 3], v[(j4 + 3) & 3],
                   d[j4 & 3], d[(j4 + 1) & 3], d[(j4 + 2) & 3],
                   yt2[j & 1]);
        }
    }
}

// ---------------------------------------------------------------------------
extern "C" void kernel_launch(void* const* d_in, const int* in_sizes, int n_in,
                              void* d_out, int out_size, void* d_ws, size_t ws_size,
                              hipStream_t stream) {
    const float* query = (const float*)d_in[0];   // (100,8,64)
    const float* value = (const float*)d_in[1];   // (8,64,256,256)
    // d_in[2..4]: unused scalars
    const float* Wl    = (const float*)d_in[5];   // (18,100)
    const float* bl    = (const float*)d_in[6];   // (18,)
    const float* Wd    = (const float*)d_in[7];   // (100,18)
    const float* bd    = (const float*)d_in[8];   // (100,)

    float* out   = (float*)d_out;
    float* qout  = out;                 // first 100*512 floats
    float* yout  = out + QN * BC;       // then 512*256*256 floats
    float* coef  = (float*)d_ws;        // 512*32 floats = 64 KB

    prep_kernel<<<BC, 128, 0, stream>>>(query, Wl, bl, Wd, bd, qout, coef);

    // 16 bands of 16 rows per image; 4 waves (bands) per block
    dim3 grid(HH / (RBAND * 4), 1, BC);
    fused_kernel<<<grid, 256, 0, stream>>>(value, coef, yout);
}